// Round 14
// baseline (1009.568 us; speedup 1.0000x reference)
//
#include <hip/hip_runtime.h>
#include <math.h>

// B=4, N=4096, C=128, DOUT=256, H=W=64 (conv out 32x32), M=1024, K=5.
// Inputs f32; output buffer f32.
#define NB 4
#define NT 4096
#define CI 128
#define DOUT 256
#define HWI 4096
#define HWO 1024
#define MC 1024
#define EPS_F 1e-6f
#define GSZ 16777216ull
#define GSZB 67108864ull

// ---------------- workspace layout (bytes) ----------------
// zero zone:
static const size_t OFF_XMAP  = 0;                          // 8388608
static const size_t OFF_CNT   = OFF_XMAP + 8388608;         // 65536
static const size_t OFF_TOT   = OFF_CNT  + 65536;           // 65536
static const size_t OFF_ALLW  = OFF_TOT  + 65536;           // 16384
static const size_t OFF_VMAX  = OFF_ALLW + 16384;           // 256
static const size_t OFF_AWDM  = OFF_VMAX + 256;             // 256
static const size_t ZERO_BYTES= OFF_AWDM + 256;
// non-zeroed:
static const size_t OFF_YMAP  = ZERO_BYTES;                 // 4194304
static const size_t OFF_XT    = OFF_YMAP + 4194304;         // 16777216
static const size_t OFF_SQ    = OFF_XT + 16777216;          // 65536
static const size_t OFF_DEN   = OFF_SQ + 65536;
static const size_t OFF_SCORE = OFF_DEN + 65536;
static const size_t OFF_WT    = OFF_SCORE + 65536;
static const size_t OFF_AWD   = OFF_WT + 65536;
static const size_t OFF_IDXD  = OFF_AWD + 65536;            // 16384
static const size_t OFF_IDXC  = OFF_IDXD + 16384;           // 65536
static const size_t OFF_INV   = OFF_IDXC + 65536;           // 65536 (written in rank_all)
static const size_t OFF_WTR   = OFF_INV + 65536;            // 1179648 (wT[1152][256])
static const size_t OFF_SWT   = OFF_WTR + 1179648;          // 131072 (swT[128][256])
static const size_t OFF_P     = OFF_SWT + 131072;           // 18874368
static const size_t OFF_G     = OFF_P + 18874368;           // ~50.2MB; +3*64MB = 239.9MiB

// ---------------- helpers ----------------
__device__ __forceinline__ float waveSum(float v){
#pragma unroll
  for (int m = 1; m < 64; m <<= 1) v += __shfl_xor(v, m, 64);
  return v;
}
__device__ __forceinline__ float blockSum256(float v, float* red){
  v = waveSum(v);
  int lane = threadIdx.x & 63, wid = threadIdx.x >> 6;
  __syncthreads();
  if (lane == 0) red[wid] = v;
  __syncthreads();
  return red[0] + red[1] + red[2] + red[3];
}
__device__ __forceinline__ void merge5(float& a0, float& a1, float& a2, float& a3, float& a4,
                                       float b0, float b1, float b2, float b3, float b4){
  float l0=a0,l1=a1,l2=a2,l3=fminf(a3,b4),l4=fminf(a4,b3),l5=b2,l6=b1,l7=b0;
  float t0=fminf(l0,l4), t4=fmaxf(l0,l4);
  float t1=fminf(l1,l5), t5=fmaxf(l1,l5);
  float t2=fminf(l2,l6), t6=fmaxf(l2,l6);
  float t3=fminf(l3,l7), t7=fmaxf(l3,l7);
  float u0=fminf(t0,t2), u2=fmaxf(t0,t2);
  float u1=fminf(t1,t3), u3=fmaxf(t1,t3);
  float u4=fminf(t4,t6);
  float u5=fminf(t5,t7);
  a0=fminf(u0,u1); a1=fmaxf(u0,u1);
  a2=fminf(u2,u3); a3=fmaxf(u2,u3);
  a4=fminf(u4,u5);
}
__device__ __forceinline__ void ins5(float v, float& t0, float& t1, float& t2, float& t3, float& t4){
  t4 = fminf(t4, v);
  float a;
  a = fminf(t3,t4); t4 = fmaxf(t3,t4); t3 = a;
  a = fminf(t2,t3); t3 = fmaxf(t2,t3); t2 = a;
  a = fminf(t1,t2); t2 = fmaxf(t1,t2); t1 = a;
  a = fminf(t0,t1); t1 = fmaxf(t0,t1); t0 = a;
}
__device__ __forceinline__ int grid_cell(float lx, float ly, int dim){
  lx = (fminf(fmaxf(lx, -1.f), 1.f) + 1.f) * 0.5f;
  ly = (fminf(fmaxf(ly, -1.f), 1.f) + 1.f) * 0.5f;
  float s = (float)(dim - 1);
  int col = (int)rintf(lx * s); col = min(max(col, 0), dim - 1);
  int row = (int)rintf(ly * s); row = min(max(row, 0), dim - 1);
  return row * dim + col;
}

// ---------------- front-end kernels ----------------
__global__ __launch_bounds__(256) void t2m_scatter(const float* __restrict__ x,
                                                   const float* __restrict__ loc,
                                                   const int* __restrict__ idx_agg,
                                                   const float* __restrict__ aggw,
                                                   float* __restrict__ xmap, float* __restrict__ cnt,
                                                   float* __restrict__ tot){
  int lin = blockIdx.x * 256 + threadIdx.x;
  int c  = lin & 127;
  int bn = lin >> 7;
  int b  = bn >> 12;
  float lx = loc[(size_t)bn*2 + 0];
  float ly = loc[(size_t)bn*2 + 1];
  int cell = grid_cell(lx, ly, 64);
  int ia = idx_agg[bn];
  float val = x[((size_t)(b*NT + ia))*CI + c];
  atomicAdd(&xmap[((size_t)(b*HWI + cell))*CI + c], val);
  if (c == 0) atomicAdd(&cnt[b*HWI + cell], 1.0f);
  if (c == 1) atomicAdd(&tot[b*NT + ia], aggw[bn]);
}

// fused weight prep: wT[k][d] = conv_w[d][k]; swT[c][d] = skip_w[d][c]
__global__ __launch_bounds__(256) void wprep_kernel(const float* __restrict__ cw, const float* __restrict__ sw,
                                                    float* __restrict__ wT, float* __restrict__ swT){
  int lin = blockIdx.x * 256 + threadIdx.x;
  if (lin < 1152*256){
    int k = lin >> 8, d = lin & 255;
    wT[lin] = cw[(size_t)d*1152 + k];
  } else {
    int i = lin - 1152*256;
    int c = i >> 8, d = i & 255;
    swT[i] = sw[d*128 + c];
  }
}

__global__ __launch_bounds__(256) void im2col_kernel(const float* __restrict__ xmap,
                                                     const float* __restrict__ cnt,
                                                     float* __restrict__ P){
  int tid = threadIdx.x;
  int c = tid & 127, n2 = tid >> 7;
  int n = blockIdx.x * 2 + n2;
  int b = n >> 10, rem = n & 1023;
  int oh = rem >> 5, ow = rem & 31;
  const float* xb = xmap + (size_t)b*HWI*CI;
  const float* cb_ = cnt + (size_t)b*HWI;
  float* prow = P + (size_t)n*1152 + c*9;
#pragma unroll
  for (int kh = 0; kh < 3; ++kh){
    int ih = oh*2 - 1 + kh;
#pragma unroll
    for (int kw = 0; kw < 3; ++kw){
      int iw = ow*2 - 1 + kw;
      bool inb = (ih >= 0) && (ih < 64) && (iw >= 0) && (iw < 64);
      float v = 0.f;
      if (inb){
        int cell = ih*64 + iw;
        v = xb[(size_t)cell*CI + c] / (cb_[cell] + EPS_F);
      }
      prow[kh*3 + kw] = v;
    }
  }
}

// conv GEMM: 64(n) x 32(d) tiles -> grid (8,64)=512 blocks. K ascending -> bit-identical.
__global__ __launch_bounds__(256) void conv_gemm(const float* __restrict__ P,
                                                 const float* __restrict__ wT,
                                                 const float* __restrict__ cb,
                                                 float* __restrict__ ymap){
  __shared__ float As[16][64];
  __shared__ float Bs[16][32];
  int n0 = blockIdx.y * 64, d0 = blockIdx.x * 32;
  int tid = threadIdx.x;
  int tx = tid & 15, ty = tid >> 4;
  int ln = tid & 63, kq = tid >> 6;
  int bkr = tid >> 3, bc4 = (tid & 7) * 4;
  float4 pav = *(const float4*)(P + (size_t)(n0+ln)*1152 + kq*4);
  float4 pbv;
  if (tid < 128) pbv = *(const float4*)(wT + (size_t)bkr*256 + d0 + bc4);
  float acc[4][2] = {{0}};
  for (int kt = 0; kt < 72; ++kt){
    __syncthreads();
    As[kq*4+0][ln]=pav.x; As[kq*4+1][ln]=pav.y; As[kq*4+2][ln]=pav.z; As[kq*4+3][ln]=pav.w;
    if (tid < 128) *(float4*)&Bs[bkr][bc4] = pbv;
    __syncthreads();
    if (kt < 71){
      int k2 = (kt + 1) * 16;
      pav = *(const float4*)(P + (size_t)(n0+ln)*1152 + k2 + kq*4);
      if (tid < 128) pbv = *(const float4*)(wT + (size_t)(k2 + bkr)*256 + d0 + bc4);
    }
#pragma unroll
    for (int k = 0; k < 16; ++k){
      float ar[4];
      *(float4*)ar = *(const float4*)&As[k][ty*4];
      float b0 = Bs[k][tx*2], b1 = Bs[k][tx*2+1];
#pragma unroll
      for (int r = 0; r < 4; ++r){ acc[r][0] += ar[r]*b0; acc[r][1] += ar[r]*b1; }
    }
  }
  float c0 = cb[d0 + tx*2], c1 = cb[d0 + tx*2 + 1];
#pragma unroll
  for (int r = 0; r < 4; ++r){
    float2 o; o.x = acc[r][0] + c0; o.y = acc[r][1] + c1;
    *(float2*)(ymap + (size_t)(n0 + ty*4 + r)*DOUT + d0 + tx*2) = o;
  }
}

// xt = x @ skip_w.T via transposed weights (coalesced); c ascending -> bit-identical
__global__ __launch_bounds__(256) void skip_kernel(const float* __restrict__ x,
                                                   const float* __restrict__ swT,
                                                   float* __restrict__ xt){
  int rowbase = blockIdx.x * 8;
  int d = threadIdx.x;
  __shared__ float xr[8*128];
  ((float4*)xr)[d] = ((const float4*)(x + (size_t)rowbase*CI))[d];
  __syncthreads();
  float acc[8] = {0,0,0,0,0,0,0,0};
  for (int c = 0; c < 128; ++c){
    float w = swT[c*256 + d];
#pragma unroll
    for (int r = 0; r < 8; ++r) acc[r] += w * xr[r*128 + c];
  }
  for (int r = 0; r < 8; ++r) xt[(size_t)(rowbase + r)*DOUT + d] = acc[r];
}

__global__ __launch_bounds__(256) void m2t_scatter(const float* __restrict__ ymap,
                                                   const float* __restrict__ loc,
                                                   const int* __restrict__ idx_agg,
                                                   const float* __restrict__ aggw,
                                                   const float* __restrict__ tot,
                                                   float* __restrict__ xt){
  int bn = blockIdx.x;
  int d = threadIdx.x;
  int b = bn >> 12;
  float lx = loc[(size_t)bn*2 + 0];
  float ly = loc[(size_t)bn*2 + 1];
  int cell = grid_cell(lx, ly, 32);
  int ia = idx_agg[bn];
  float w = aggw[bn] / (tot[b*NT + ia] + EPS_F);
  float val = ymap[((size_t)(b*HWO + cell))*DOUT + d] * w;
  atomicAdd(&xt[((size_t)(b*NT + ia))*DOUT + d], val);
}

__global__ __launch_bounds__(256) void ln_kernel(float* __restrict__ xt,
                                                 const float* __restrict__ g,
                                                 const float* __restrict__ bta,
                                                 const float* __restrict__ cw,
                                                 const float* __restrict__ cb,
                                                 float* __restrict__ sq, float* __restrict__ wt){
  __shared__ float red[4];
  int row = blockIdx.x;
  int d = threadIdx.x;
  float v = xt[(size_t)row*DOUT + d];
  float mu = blockSum256(v, red) * (1.0f/256.0f);
  float xc = v - mu;
  float var = blockSum256(xc*xc, red) * (1.0f/256.0f);
  float rn = 1.0f / sqrtf(var + 1e-5f);
  float y = xc * rn * g[d] + bta[d];
  xt[(size_t)row*DOUT + d] = y;
  float s2 = blockSum256(y*y, red);
  float cf = blockSum256(y*cw[d], red);
  if (d == 0){ sq[row] = s2; wt[row] = expf(cf + cb[0]); }
}

// ---------------- clustering ----------------
// gram: 64x64 lower-triangle tiles (2080/batch), BK=16, prefetch.
// LDS union: As[16][64]@0, Bs[16][64]@1024, T[64][65] aliases (16.6 KB).
__global__ __launch_bounds__(256) void gram64(const float* __restrict__ xt, float* __restrict__ G,
                                              int b_base, size_t gstride){
  __shared__ float smem[4160];
  int b = b_base + blockIdx.y;
  const float* A = xt + (size_t)b*NT*DOUT;
  float* Gb = G + (size_t)blockIdx.y*gstride;
  int t = blockIdx.x;
  int ti = 0, accu = 0;
  while (accu + ti + 1 <= t){ accu += ti + 1; ++ti; }
  int tj = t - accu;
  int i0 = ti * 64, j0 = tj * 64;
  int tid = threadIdx.x;
  int li = tid & 63, kq = tid >> 6;
  int tx = tid & 15, ty = tid >> 4;
  float4 av = *(const float4*)(A + (size_t)(i0+li)*DOUT + kq*4);
  float4 bv = *(const float4*)(A + (size_t)(j0+li)*DOUT + kq*4);
  float acc[4][4] = {{0}};
  for (int kt = 0; kt < 256; kt += 16){
    __syncthreads();
    smem[(kq*4+0)*64 + li]=av.x; smem[(kq*4+1)*64 + li]=av.y;
    smem[(kq*4+2)*64 + li]=av.z; smem[(kq*4+3)*64 + li]=av.w;
    smem[1024 + (kq*4+0)*64 + li]=bv.x; smem[1024 + (kq*4+1)*64 + li]=bv.y;
    smem[1024 + (kq*4+2)*64 + li]=bv.z; smem[1024 + (kq*4+3)*64 + li]=bv.w;
    __syncthreads();
    if (kt < 240){
      av = *(const float4*)(A + (size_t)(i0+li)*DOUT + kt + 16 + kq*4);
      bv = *(const float4*)(A + (size_t)(j0+li)*DOUT + kt + 16 + kq*4);
    }
#pragma unroll
    for (int k = 0; k < 16; ++k){
      float ar[4], br[4];
      *(float4*)ar = *(const float4*)&smem[k*64 + ty*4];
      *(float4*)br = *(const float4*)&smem[1024 + k*64 + tx*4];
#pragma unroll
      for (int r = 0; r < 4; ++r)
#pragma unroll
        for (int s = 0; s < 4; ++s) acc[r][s] += ar[r]*br[s];
    }
  }
#pragma unroll
  for (int r = 0; r < 4; ++r)
    *(float4*)(Gb + (size_t)(i0 + ty*4 + r)*NT + j0 + tx*4) = *(float4*)&acc[r][0];
  if (ti != tj){
    __syncthreads();
#pragma unroll
    for (int r = 0; r < 4; ++r)
#pragma unroll
      for (int s = 0; s < 4; ++s) smem[(ty*4+r)*65 + tx*4+s] = acc[r][s];
    __syncthreads();
#pragma unroll
    for (int r = 0; r < 4; ++r){
      float4 o;
      o.x = smem[(tx*4+0)*65 + ty*4+r]; o.y = smem[(tx*4+1)*65 + ty*4+r];
      o.z = smem[(tx*4+2)*65 + ty*4+r]; o.w = smem[(tx*4+3)*65 + ty*4+r];
      *(float4*)(Gb + (size_t)(j0 + ty*4 + r)*NT + i0 + tx*4) = o;
    }
  }
}

__global__ __launch_bounds__(256) void density_all(const float* __restrict__ G, size_t gstride,
                                                   const float* __restrict__ sq,
                                                   float* __restrict__ density, int* __restrict__ vmax,
                                                   int b_base){
  int b = b_base + blockIdx.y;
  const float* Gb = G + (size_t)blockIdx.y*gstride;
  int i = blockIdx.x;
  int tid = threadIdx.x;
  const float* sqb = sq + b*NT;
  float sqi = sqb[i];
  const float* row = Gb + (size_t)i*NT;
  float t0=INFINITY,t1=INFINITY,t2=INFINITY,t3=INFINITY,t4=INFINITY;
  float vmx = 0.f;
  for (int j = tid*4; j < NT; j += 1024){
    float4 g4 = *(const float4*)(row + j);
    float4 s4 = *(const float4*)(sqb + j);
    float v0 = fmaxf(sqi + s4.x - 2.0f*g4.x, 0.0f);
    float v1 = fmaxf(sqi + s4.y - 2.0f*g4.y, 0.0f);
    float v2 = fmaxf(sqi + s4.z - 2.0f*g4.z, 0.0f);
    float v3 = fmaxf(sqi + s4.w - 2.0f*g4.w, 0.0f);
    vmx = fmaxf(fmaxf(vmx, fmaxf(v0,v1)), fmaxf(v2,v3));
    ins5(v0,t0,t1,t2,t3,t4); ins5(v1,t0,t1,t2,t3,t4);
    ins5(v2,t0,t1,t2,t3,t4); ins5(v3,t0,t1,t2,t3,t4);
  }
#pragma unroll
  for (int m = 1; m < 64; m <<= 1){
    float b0=__shfl_xor(t0,m,64), b1=__shfl_xor(t1,m,64), b2=__shfl_xor(t2,m,64),
          b3=__shfl_xor(t3,m,64), b4=__shfl_xor(t4,m,64);
    merge5(t0,t1,t2,t3,t4,b0,b1,b2,b3,b4);
    vmx = fmaxf(vmx, __shfl_xor(vmx,m,64));
  }
  __shared__ float w5[4][5];
  __shared__ float wm[4];
  int lane = tid & 63, wid = tid >> 6;
  if (lane == 0){ w5[wid][0]=t0; w5[wid][1]=t1; w5[wid][2]=t2; w5[wid][3]=t3; w5[wid][4]=t4; wm[wid]=vmx; }
  __syncthreads();
  if (tid == 0){
    float a0=w5[0][0],a1=w5[0][1],a2=w5[0][2],a3=w5[0][3],a4=w5[0][4];
    for (int w = 1; w < 4; ++w) merge5(a0,a1,a2,a3,a4, w5[w][0],w5[w][1],w5[w][2],w5[w][3],w5[w][4]);
    float d0=sqrtf(a0)*0.0625f, d1=sqrtf(a1)*0.0625f, d2=sqrtf(a2)*0.0625f,
          d3=sqrtf(a3)*0.0625f, d4=sqrtf(a4)*0.0625f;
    float s = d0*d0; s += d1*d1; s += d2*d2; s += d3*d3; s += d4*d4;
    density[b*NT + i] = expf(-(s / 5.0f));
    float vm = fmaxf(fmaxf(wm[0],wm[1]), fmaxf(wm[2],wm[3]));
    atomicMax(vmax + b, __float_as_int(vm));
  }
}

__global__ __launch_bounds__(256) void parent_all(const float* __restrict__ G, size_t gstride,
                                                  const float* __restrict__ sq,
                                                  const float* __restrict__ density, const int* __restrict__ vmax,
                                                  float* __restrict__ score, int b_base){
  int b = b_base + blockIdx.y;
  const float* Gb = G + (size_t)blockIdx.y*gstride;
  int i = blockIdx.x;
  int tid = threadIdx.x;
  const float* sqb = sq + b*NT;
  const float* den = density + b*NT;
  float sqi = sqb[i];
  float di = den[i];
  const float* row = Gb + (size_t)i*NT;
  float minv = INFINITY;
  for (int j = tid*4; j < NT; j += 1024){
    float4 g4 = *(const float4*)(row + j);
    float4 s4 = *(const float4*)(sqb + j);
    float4 d4 = *(const float4*)(den + j);
    float v0 = fmaxf(sqi + s4.x - 2.0f*g4.x, 0.0f);
    float v1 = fmaxf(sqi + s4.y - 2.0f*g4.y, 0.0f);
    float v2 = fmaxf(sqi + s4.z - 2.0f*g4.z, 0.0f);
    float v3 = fmaxf(sqi + s4.w - 2.0f*g4.w, 0.0f);
    minv = fminf(minv, (d4.x > di) ? v0 : INFINITY);
    minv = fminf(minv, (d4.y > di) ? v1 : INFINITY);
    minv = fminf(minv, (d4.z > di) ? v2 : INFINITY);
    minv = fminf(minv, (d4.w > di) ? v3 : INFINITY);
  }
#pragma unroll
  for (int m = 1; m < 64; m <<= 1) minv = fminf(minv, __shfl_xor(minv,m,64));
  __shared__ float wmn[4];
  int lane = tid & 63, wid = tid >> 6;
  if (lane == 0) wmn[wid] = minv;
  __syncthreads();
  if (tid == 0){
    float mv = fminf(fminf(wmn[0],wmn[1]), fminf(wmn[2],wmn[3]));
    float dmax = sqrtf(__int_as_float(vmax[b])) * 0.0625f;
    float dp = isinf(mv) ? dmax : sqrtf(mv) * 0.0625f;
    score[b*NT + i] = dp * di;
  }
}

// exact rank selection: rank_i = #{j: s_j > s_i} + #{j: s_j == s_i && j < i}.
// Same stable order as (score desc, idx asc) -> identical idx_down/inv.
// UNROLL 8: keeps 8 independent ds_read_b128 in flight (round-13 regression was
// the un-unrolled loop exposing ~120cyc LDS latency per iteration).
__global__ __launch_bounds__(256) void rank_all(const float* __restrict__ score, int* __restrict__ idx_down,
                                                int* __restrict__ inv, int b_base){
  __shared__ float s[4096];
  int b = b_base + blockIdx.y;
  int tid = threadIdx.x;
  for (int t = tid; t < 4096; t += 256) s[t] = score[b*NT + t];
  __syncthreads();
  int i = blockIdx.x * 256 + tid;
  float si = s[i];
  int rank = 0;
#pragma unroll 8
  for (int j = 0; j < 4096; j += 4){
    float4 v = *(const float4*)&s[j];
    rank += (v.x > si) || (v.x == si && (j+0) < i);
    rank += (v.y > si) || (v.y == si && (j+1) < i);
    rank += (v.z > si) || (v.z == si && (j+2) < i);
    rank += (v.w > si) || (v.w == si && (j+3) < i);
  }
  inv[b*NT + i] = (rank < MC) ? rank : -1;
  if (rank < MC) idx_down[b*MC + rank] = i;
}

// assign: block = 16 j x 16 m-chunks (64 m each, ascending); grid 256 x gy.
__global__ __launch_bounds__(256) void assign_all(const float* __restrict__ G, size_t gstride,
                                                  const float* __restrict__ sq,
                                                  const int* __restrict__ idx_down, const int* __restrict__ inv,
                                                  const float* __restrict__ wt,
                                                  int* __restrict__ idx_cluster, float* __restrict__ allw,
                                                  int b_base){
  int b = b_base + blockIdx.y;
  const float* Gb = G + (size_t)blockIdx.y*gstride;
  int jl = threadIdx.x & 15, mq = threadIdx.x >> 4;
  int j = blockIdx.x * 16 + jl;
  const float* sqb = sq + b*NT;
  float sqj = sqb[j];
  const int* idb = idx_down + b*MC;
  float bestd = INFINITY; int bestm = 0x7fffffff;
  for (int m = mq*64; m < mq*64 + 64; ++m){
    int im = idb[m];
    float g = Gb[(size_t)im*NT + j];
    float v = fmaxf(sqb[im] + sqj - 2.0f*g, 0.0f);
    float d = sqrtf(v) * 0.0625f;
    if (d < bestd){ bestd = d; bestm = m; }
  }
  __shared__ float ld[16][17];
  __shared__ int lm[16][17];
  ld[mq][jl] = bestd; lm[mq][jl] = bestm;
  __syncthreads();
  if (mq == 0){
    for (int q = 1; q < 16; ++q){
      float d2 = ld[q][jl]; int m2 = lm[q][jl];
      if (d2 < bestd || (d2 == bestd && m2 < bestm)){ bestd = d2; bestm = m2; }
    }
    int iv = inv[b*NT + j];
    int final_m = (iv >= 0) ? iv : bestm;
    idx_cluster[b*NT + j] = final_m;
    atomicAdd(&allw[b*MC + final_m], wt[b*NT + j]);
  }
}

// ---------------- merge + outputs ----------------
__global__ __launch_bounds__(256) void xdown_kernel(const int* __restrict__ idx_cluster,
                                                    const float* __restrict__ wt, const float* __restrict__ allw,
                                                    const float* __restrict__ xt, float* __restrict__ out0){
  int bn = blockIdx.x;
  int d = threadIdx.x;
  int b = bn >> 12;
  int ic = idx_cluster[bn];
  float nw = wt[bn] / (allw[b*MC + ic] + EPS_F);
  float v = xt[(size_t)bn*DOUT + d] * nw;
  atomicAdd(&out0[((size_t)(b*MC + ic))*DOUT + d], v);
}
__global__ __launch_bounds__(256) void out12a_kernel(const int* __restrict__ idx_agg, const int* __restrict__ idx_cluster,
                                                     const float* __restrict__ aggw,
                                                     const float* __restrict__ wt, const float* __restrict__ allw,
                                                     float* __restrict__ awd, int* __restrict__ awdmax,
                                                     float* __restrict__ out1){
  __shared__ float red[4];
  int lin = blockIdx.x * 256 + threadIdx.x;
  int b = lin >> 12;
  int ia = idx_agg[lin];
  int ic = idx_cluster[b*NT + ia];
  out1[lin] = (float)ic;
  float nw = wt[b*NT + ia] / (allw[b*MC + ic] + EPS_F);
  float v = aggw[lin] * nw;
  awd[lin] = v;
  float wv = v;
#pragma unroll
  for (int m = 1; m < 64; m <<= 1) wv = fmaxf(wv, __shfl_xor(wv, m, 64));
  int lane = threadIdx.x & 63, wid = threadIdx.x >> 6;
  if (lane == 0) red[wid] = wv;
  __syncthreads();
  if (threadIdx.x == 0){
    float bm = fmaxf(fmaxf(red[0], red[1]), fmaxf(red[2], red[3]));
    atomicMax(&awdmax[b], __float_as_int(bm));
  }
}
__global__ __launch_bounds__(256) void out2_kernel(const float* __restrict__ awd, const int* __restrict__ awdmax,
                                                   float* __restrict__ out2){
  int lin = blockIdx.x * 256 + threadIdx.x;
  int b = lin >> 12;
  out2[lin] = awd[lin] / __int_as_float(awdmax[b]);
}

extern "C" void kernel_launch(void* const* d_in, const int* in_sizes, int n_in,
                              void* d_out, int out_size, void* d_ws, size_t ws_size,
                              hipStream_t stream) {
  const float* x      = (const float*)d_in[0];
  const float* loc    = (const float*)d_in[1];
  const int*   idxagg = (const int*)d_in[2];
  const float* aggw   = (const float*)d_in[3];
  const float* convw  = (const float*)d_in[7];
  const float* convb  = (const float*)d_in[8];
  const float* skipw  = (const float*)d_in[9];
  const float* lng    = (const float*)d_in[10];
  const float* lnb    = (const float*)d_in[11];
  const float* confw  = (const float*)d_in[12];
  const float* confb  = (const float*)d_in[13];

  char* ws = (char*)d_ws;
  float* w_xmap  = (float*)(ws + OFF_XMAP);
  float* w_cnt   = (float*)(ws + OFF_CNT);
  float* w_tot   = (float*)(ws + OFF_TOT);
  float* w_allw  = (float*)(ws + OFF_ALLW);
  int*   w_vmax  = (int*)  (ws + OFF_VMAX);
  int*   w_awdm  = (int*)  (ws + OFF_AWDM);
  float* w_ymap  = (float*)(ws + OFF_YMAP);
  float* w_xt    = (float*)(ws + OFF_XT);
  float* w_sq    = (float*)(ws + OFF_SQ);
  float* w_den   = (float*)(ws + OFF_DEN);
  float* w_score = (float*)(ws + OFF_SCORE);
  float* w_wt    = (float*)(ws + OFF_WT);
  float* w_awd   = (float*)(ws + OFF_AWD);
  int*   w_idxd  = (int*)  (ws + OFF_IDXD);
  int*   w_idxc  = (int*)  (ws + OFF_IDXC);
  int*   w_inv   = (int*)  (ws + OFF_INV);
  float* w_wtr   = (float*)(ws + OFF_WTR);
  float* w_swt   = (float*)(ws + OFF_SWT);
  float* w_p     = (float*)(ws + OFF_P);
  float* w_g     = (float*)(ws + OFF_G);

  int gcount = 1;
  for (int k = 4; k >= 1; --k){
    if (OFF_G + (size_t)k*GSZB <= ws_size){ gcount = k; break; }
  }

  float* out0 = (float*)d_out;
  float* out1 = out0 + NB*MC*DOUT;
  float* out2 = out1 + NB*NT;

  hipMemsetAsync(ws, 0, ZERO_BYTES, stream);
  hipMemsetAsync(out0, 0, (size_t)NB*MC*DOUT*sizeof(float), stream);

  t2m_scatter<<<NB*NT*CI/256, 256, 0, stream>>>(x, loc, idxagg, aggw, w_xmap, w_cnt, w_tot);
  wprep_kernel<<<1280, 256, 0, stream>>>(convw, skipw, w_wtr, w_swt);
  im2col_kernel<<<2048, 256, 0, stream>>>(w_xmap, w_cnt, w_p);
  conv_gemm<<<dim3(8, 64), 256, 0, stream>>>(w_p, w_wtr, convb, w_ymap);
  skip_kernel<<<NB*NT/8, 256, 0, stream>>>(x, w_swt, w_xt);
  m2t_scatter<<<NB*NT, 256, 0, stream>>>(w_ymap, loc, idxagg, aggw, w_tot, w_xt);
  ln_kernel<<<NB*NT, 256, 0, stream>>>(w_xt, lng, lnb, confw, confb, w_sq, w_wt);

  for (int g0 = 0; g0 < NB; g0 += gcount){
    int gy = (NB - g0 < gcount) ? (NB - g0) : gcount;
    gram64     <<<dim3(2080, gy), 256, 0, stream>>>(w_xt, w_g, g0, GSZ);
    density_all<<<dim3(NT, gy), 256, 0, stream>>>(w_g, GSZ, w_sq, w_den, w_vmax, g0);
    parent_all <<<dim3(NT, gy), 256, 0, stream>>>(w_g, GSZ, w_sq, w_den, w_vmax, w_score, g0);
    rank_all   <<<dim3(16, gy), 256, 0, stream>>>(w_score, w_idxd, w_inv, g0);
    assign_all <<<dim3(256, gy), 256, 0, stream>>>(w_g, GSZ, w_sq, w_idxd, w_inv, w_wt, w_idxc, w_allw, g0);
  }

  xdown_kernel<<<NB*NT, 256, 0, stream>>>(w_idxc, w_wt, w_allw, w_xt, out0);
  out12a_kernel<<<NB*NT/256, 256, 0, stream>>>(idxagg, w_idxc, aggw, w_wt, w_allw, w_awd, w_awdm, out1);
  out2_kernel<<<NB*NT/256, 256, 0, stream>>>(w_awd, w_awdm, out2);

  (void)in_sizes; (void)n_in; (void)out_size;
}

// Round 15
// 863.242 us; speedup vs baseline: 1.1695x; 1.1695x over previous
//
#include <hip/hip_runtime.h>
#include <math.h>

// B=4, N=4096, C=128, DOUT=256, H=W=64 (conv out 32x32), M=1024, K=5.
// Inputs f32; output buffer f32.
#define NB 4
#define NT 4096
#define CI 128
#define DOUT 256
#define HWI 4096
#define HWO 1024
#define MC 1024
#define EPS_F 1e-6f
#define GSZ 16777216ull
#define GSZB 67108864ull

// ---------------- workspace layout (bytes) ----------------
// zero zone:
static const size_t OFF_XMAP  = 0;                          // 8388608
static const size_t OFF_CNT   = OFF_XMAP + 8388608;         // 65536
static const size_t OFF_TOT   = OFF_CNT  + 65536;           // 65536
static const size_t OFF_ALLW  = OFF_TOT  + 65536;           // 16384
static const size_t OFF_VMAX  = OFF_ALLW + 16384;           // 256
static const size_t OFF_AWDM  = OFF_VMAX + 256;             // 256
static const size_t ZERO_BYTES= OFF_AWDM + 256;
// non-zeroed:
static const size_t OFF_YMAP  = ZERO_BYTES;                 // 4194304
static const size_t OFF_XT    = OFF_YMAP + 4194304;         // 16777216
static const size_t OFF_SQ    = OFF_XT + 16777216;          // 65536
static const size_t OFF_DEN   = OFF_SQ + 65536;
static const size_t OFF_SCORE = OFF_DEN + 65536;
static const size_t OFF_WT    = OFF_SCORE + 65536;
static const size_t OFF_AWD   = OFF_WT + 65536;
static const size_t OFF_IDXD  = OFF_AWD + 65536;            // 16384
static const size_t OFF_IDXC  = OFF_IDXD + 16384;           // 65536
static const size_t OFF_INV   = OFF_IDXC + 65536;           // 65536 (init in topk)
static const size_t OFF_WTR   = OFF_INV + 65536;            // 1179648 (wT[1152][256])
static const size_t OFF_SWT   = OFF_WTR + 1179648;          // 131072 (swT[128][256])
static const size_t OFF_P     = OFF_SWT + 131072;           // 18874368
static const size_t OFF_G     = OFF_P + 18874368;           // ~50.2MB; +3*64MB = 239.9MiB

// ---------------- helpers ----------------
__device__ __forceinline__ float waveSum(float v){
#pragma unroll
  for (int m = 1; m < 64; m <<= 1) v += __shfl_xor(v, m, 64);
  return v;
}
__device__ __forceinline__ float blockSum256(float v, float* red){
  v = waveSum(v);
  int lane = threadIdx.x & 63, wid = threadIdx.x >> 6;
  __syncthreads();
  if (lane == 0) red[wid] = v;
  __syncthreads();
  return red[0] + red[1] + red[2] + red[3];
}
__device__ __forceinline__ void merge5(float& a0, float& a1, float& a2, float& a3, float& a4,
                                       float b0, float b1, float b2, float b3, float b4){
  float l0=a0,l1=a1,l2=a2,l3=fminf(a3,b4),l4=fminf(a4,b3),l5=b2,l6=b1,l7=b0;
  float t0=fminf(l0,l4), t4=fmaxf(l0,l4);
  float t1=fminf(l1,l5), t5=fmaxf(l1,l5);
  float t2=fminf(l2,l6), t6=fmaxf(l2,l6);
  float t3=fminf(l3,l7), t7=fmaxf(l3,l7);
  float u0=fminf(t0,t2), u2=fmaxf(t0,t2);
  float u1=fminf(t1,t3), u3=fmaxf(t1,t3);
  float u4=fminf(t4,t6);
  float u5=fminf(t5,t7);
  a0=fminf(u0,u1); a1=fmaxf(u0,u1);
  a2=fminf(u2,u3); a3=fmaxf(u2,u3);
  a4=fminf(u4,u5);
}
__device__ __forceinline__ void ins5(float v, float& t0, float& t1, float& t2, float& t3, float& t4){
  t4 = fminf(t4, v);
  float a;
  a = fminf(t3,t4); t4 = fmaxf(t3,t4); t3 = a;
  a = fminf(t2,t3); t3 = fmaxf(t2,t3); t2 = a;
  a = fminf(t1,t2); t2 = fmaxf(t1,t2); t1 = a;
  a = fminf(t0,t1); t1 = fmaxf(t0,t1); t0 = a;
}
__device__ __forceinline__ int grid_cell(float lx, float ly, int dim){
  lx = (fminf(fmaxf(lx, -1.f), 1.f) + 1.f) * 0.5f;
  ly = (fminf(fmaxf(ly, -1.f), 1.f) + 1.f) * 0.5f;
  float s = (float)(dim - 1);
  int col = (int)rintf(lx * s); col = min(max(col, 0), dim - 1);
  int row = (int)rintf(ly * s); row = min(max(row, 0), dim - 1);
  return row * dim + col;
}

// ---------------- front-end kernels ----------------
__global__ __launch_bounds__(256) void t2m_scatter(const float* __restrict__ x,
                                                   const float* __restrict__ loc,
                                                   const int* __restrict__ idx_agg,
                                                   const float* __restrict__ aggw,
                                                   float* __restrict__ xmap, float* __restrict__ cnt,
                                                   float* __restrict__ tot){
  int lin = blockIdx.x * 256 + threadIdx.x;
  int c  = lin & 127;
  int bn = lin >> 7;
  int b  = bn >> 12;
  float lx = loc[(size_t)bn*2 + 0];
  float ly = loc[(size_t)bn*2 + 1];
  int cell = grid_cell(lx, ly, 64);
  int ia = idx_agg[bn];
  float val = x[((size_t)(b*NT + ia))*CI + c];
  atomicAdd(&xmap[((size_t)(b*HWI + cell))*CI + c], val);
  if (c == 0) atomicAdd(&cnt[b*HWI + cell], 1.0f);
  if (c == 1) atomicAdd(&tot[b*NT + ia], aggw[bn]);
}

// fused weight prep: wT[k][d] = conv_w[d][k]; swT[c][d] = skip_w[d][c]
__global__ __launch_bounds__(256) void wprep_kernel(const float* __restrict__ cw, const float* __restrict__ sw,
                                                    float* __restrict__ wT, float* __restrict__ swT){
  int lin = blockIdx.x * 256 + threadIdx.x;
  if (lin < 1152*256){
    int k = lin >> 8, d = lin & 255;
    wT[lin] = cw[(size_t)d*1152 + k];
  } else {
    int i = lin - 1152*256;
    int c = i >> 8, d = i & 255;
    swT[i] = sw[d*128 + c];
  }
}

__global__ __launch_bounds__(256) void im2col_kernel(const float* __restrict__ xmap,
                                                     const float* __restrict__ cnt,
                                                     float* __restrict__ P){
  int tid = threadIdx.x;
  int c = tid & 127, n2 = tid >> 7;
  int n = blockIdx.x * 2 + n2;
  int b = n >> 10, rem = n & 1023;
  int oh = rem >> 5, ow = rem & 31;
  const float* xb = xmap + (size_t)b*HWI*CI;
  const float* cb_ = cnt + (size_t)b*HWI;
  float* prow = P + (size_t)n*1152 + c*9;
#pragma unroll
  for (int kh = 0; kh < 3; ++kh){
    int ih = oh*2 - 1 + kh;
#pragma unroll
    for (int kw = 0; kw < 3; ++kw){
      int iw = ow*2 - 1 + kw;
      bool inb = (ih >= 0) && (ih < 64) && (iw >= 0) && (iw < 64);
      float v = 0.f;
      if (inb){
        int cell = ih*64 + iw;
        v = xb[(size_t)cell*CI + c] / (cb_[cell] + EPS_F);
      }
      prow[kh*3 + kw] = v;
    }
  }
}

// conv GEMM: 64(n) x 32(d) tiles -> grid (8,64)=512 blocks. K ascending -> bit-identical.
__global__ __launch_bounds__(256) void conv_gemm(const float* __restrict__ P,
                                                 const float* __restrict__ wT,
                                                 const float* __restrict__ cb,
                                                 float* __restrict__ ymap){
  __shared__ float As[16][64];
  __shared__ float Bs[16][32];
  int n0 = blockIdx.y * 64, d0 = blockIdx.x * 32;
  int tid = threadIdx.x;
  int tx = tid & 15, ty = tid >> 4;
  int ln = tid & 63, kq = tid >> 6;
  int bkr = tid >> 3, bc4 = (tid & 7) * 4;
  float4 pav = *(const float4*)(P + (size_t)(n0+ln)*1152 + kq*4);
  float4 pbv;
  if (tid < 128) pbv = *(const float4*)(wT + (size_t)bkr*256 + d0 + bc4);
  float acc[4][2] = {{0}};
  for (int kt = 0; kt < 72; ++kt){
    __syncthreads();
    As[kq*4+0][ln]=pav.x; As[kq*4+1][ln]=pav.y; As[kq*4+2][ln]=pav.z; As[kq*4+3][ln]=pav.w;
    if (tid < 128) *(float4*)&Bs[bkr][bc4] = pbv;
    __syncthreads();
    if (kt < 71){
      int k2 = (kt + 1) * 16;
      pav = *(const float4*)(P + (size_t)(n0+ln)*1152 + k2 + kq*4);
      if (tid < 128) pbv = *(const float4*)(wT + (size_t)(k2 + bkr)*256 + d0 + bc4);
    }
#pragma unroll
    for (int k = 0; k < 16; ++k){
      float ar[4];
      *(float4*)ar = *(const float4*)&As[k][ty*4];
      float b0 = Bs[k][tx*2], b1 = Bs[k][tx*2+1];
#pragma unroll
      for (int r = 0; r < 4; ++r){ acc[r][0] += ar[r]*b0; acc[r][1] += ar[r]*b1; }
    }
  }
  float c0 = cb[d0 + tx*2], c1 = cb[d0 + tx*2 + 1];
#pragma unroll
  for (int r = 0; r < 4; ++r){
    float2 o; o.x = acc[r][0] + c0; o.y = acc[r][1] + c1;
    *(float2*)(ymap + (size_t)(n0 + ty*4 + r)*DOUT + d0 + tx*2) = o;
  }
}

// xt = x @ skip_w.T via transposed weights (coalesced); c ascending -> bit-identical
__global__ __launch_bounds__(256) void skip_kernel(const float* __restrict__ x,
                                                   const float* __restrict__ swT,
                                                   float* __restrict__ xt){
  int rowbase = blockIdx.x * 8;
  int d = threadIdx.x;
  __shared__ float xr[8*128];
  ((float4*)xr)[d] = ((const float4*)(x + (size_t)rowbase*CI))[d];
  __syncthreads();
  float acc[8] = {0,0,0,0,0,0,0,0};
  for (int c = 0; c < 128; ++c){
    float w = swT[c*256 + d];
#pragma unroll
    for (int r = 0; r < 8; ++r) acc[r] += w * xr[r*128 + c];
  }
  for (int r = 0; r < 8; ++r) xt[(size_t)(rowbase + r)*DOUT + d] = acc[r];
}

__global__ __launch_bounds__(256) void m2t_scatter(const float* __restrict__ ymap,
                                                   const float* __restrict__ loc,
                                                   const int* __restrict__ idx_agg,
                                                   const float* __restrict__ aggw,
                                                   const float* __restrict__ tot,
                                                   float* __restrict__ xt){
  int bn = blockIdx.x;
  int d = threadIdx.x;
  int b = bn >> 12;
  float lx = loc[(size_t)bn*2 + 0];
  float ly = loc[(size_t)bn*2 + 1];
  int cell = grid_cell(lx, ly, 32);
  int ia = idx_agg[bn];
  float w = aggw[bn] / (tot[b*NT + ia] + EPS_F);
  float val = ymap[((size_t)(b*HWO + cell))*DOUT + d] * w;
  atomicAdd(&xt[((size_t)(b*NT + ia))*DOUT + d], val);
}

__global__ __launch_bounds__(256) void ln_kernel(float* __restrict__ xt,
                                                 const float* __restrict__ g,
                                                 const float* __restrict__ bta,
                                                 const float* __restrict__ cw,
                                                 const float* __restrict__ cb,
                                                 float* __restrict__ sq, float* __restrict__ wt){
  __shared__ float red[4];
  int row = blockIdx.x;
  int d = threadIdx.x;
  float v = xt[(size_t)row*DOUT + d];
  float mu = blockSum256(v, red) * (1.0f/256.0f);
  float xc = v - mu;
  float var = blockSum256(xc*xc, red) * (1.0f/256.0f);
  float rn = 1.0f / sqrtf(var + 1e-5f);
  float y = xc * rn * g[d] + bta[d];
  xt[(size_t)row*DOUT + d] = y;
  float s2 = blockSum256(y*y, red);
  float cf = blockSum256(y*cw[d], red);
  if (d == 0){ sq[row] = s2; wt[row] = expf(cf + cb[0]); }
}

// ---------------- clustering ----------------
// gram: 64x64 lower-triangle tiles (2080/batch), BK=16, prefetch.
// LDS union: As[16][64]@0, Bs[16][64]@1024, T[64][65] aliases (16.6 KB).
__global__ __launch_bounds__(256) void gram64(const float* __restrict__ xt, float* __restrict__ G,
                                              int b_base, size_t gstride){
  __shared__ float smem[4160];
  int b = b_base + blockIdx.y;
  const float* A = xt + (size_t)b*NT*DOUT;
  float* Gb = G + (size_t)blockIdx.y*gstride;
  int t = blockIdx.x;
  int ti = 0, accu = 0;
  while (accu + ti + 1 <= t){ accu += ti + 1; ++ti; }
  int tj = t - accu;
  int i0 = ti * 64, j0 = tj * 64;
  int tid = threadIdx.x;
  int li = tid & 63, kq = tid >> 6;
  int tx = tid & 15, ty = tid >> 4;
  float4 av = *(const float4*)(A + (size_t)(i0+li)*DOUT + kq*4);
  float4 bv = *(const float4*)(A + (size_t)(j0+li)*DOUT + kq*4);
  float acc[4][4] = {{0}};
  for (int kt = 0; kt < 256; kt += 16){
    __syncthreads();
    smem[(kq*4+0)*64 + li]=av.x; smem[(kq*4+1)*64 + li]=av.y;
    smem[(kq*4+2)*64 + li]=av.z; smem[(kq*4+3)*64 + li]=av.w;
    smem[1024 + (kq*4+0)*64 + li]=bv.x; smem[1024 + (kq*4+1)*64 + li]=bv.y;
    smem[1024 + (kq*4+2)*64 + li]=bv.z; smem[1024 + (kq*4+3)*64 + li]=bv.w;
    __syncthreads();
    if (kt < 240){
      av = *(const float4*)(A + (size_t)(i0+li)*DOUT + kt + 16 + kq*4);
      bv = *(const float4*)(A + (size_t)(j0+li)*DOUT + kt + 16 + kq*4);
    }
#pragma unroll
    for (int k = 0; k < 16; ++k){
      float ar[4], br[4];
      *(float4*)ar = *(const float4*)&smem[k*64 + ty*4];
      *(float4*)br = *(const float4*)&smem[1024 + k*64 + tx*4];
#pragma unroll
      for (int r = 0; r < 4; ++r)
#pragma unroll
        for (int s = 0; s < 4; ++s) acc[r][s] += ar[r]*br[s];
    }
  }
#pragma unroll
  for (int r = 0; r < 4; ++r)
    *(float4*)(Gb + (size_t)(i0 + ty*4 + r)*NT + j0 + tx*4) = *(float4*)&acc[r][0];
  if (ti != tj){
    __syncthreads();
#pragma unroll
    for (int r = 0; r < 4; ++r)
#pragma unroll
      for (int s = 0; s < 4; ++s) smem[(ty*4+r)*65 + tx*4+s] = acc[r][s];
    __syncthreads();
#pragma unroll
    for (int r = 0; r < 4; ++r){
      float4 o;
      o.x = smem[(tx*4+0)*65 + ty*4+r]; o.y = smem[(tx*4+1)*65 + ty*4+r];
      o.z = smem[(tx*4+2)*65 + ty*4+r]; o.w = smem[(tx*4+3)*65 + ty*4+r];
      *(float4*)(Gb + (size_t)(j0 + ty*4 + r)*NT + i0 + tx*4) = o;
    }
  }
}

__global__ __launch_bounds__(256) void density_all(const float* __restrict__ G, size_t gstride,
                                                   const float* __restrict__ sq,
                                                   float* __restrict__ density, int* __restrict__ vmax,
                                                   int b_base){
  int b = b_base + blockIdx.y;
  const float* Gb = G + (size_t)blockIdx.y*gstride;
  int i = blockIdx.x;
  int tid = threadIdx.x;
  const float* sqb = sq + b*NT;
  float sqi = sqb[i];
  const float* row = Gb + (size_t)i*NT;
  float t0=INFINITY,t1=INFINITY,t2=INFINITY,t3=INFINITY,t4=INFINITY;
  float vmx = 0.f;
  for (int j = tid*4; j < NT; j += 1024){
    float4 g4 = *(const float4*)(row + j);
    float4 s4 = *(const float4*)(sqb + j);
    float v0 = fmaxf(sqi + s4.x - 2.0f*g4.x, 0.0f);
    float v1 = fmaxf(sqi + s4.y - 2.0f*g4.y, 0.0f);
    float v2 = fmaxf(sqi + s4.z - 2.0f*g4.z, 0.0f);
    float v3 = fmaxf(sqi + s4.w - 2.0f*g4.w, 0.0f);
    vmx = fmaxf(fmaxf(vmx, fmaxf(v0,v1)), fmaxf(v2,v3));
    ins5(v0,t0,t1,t2,t3,t4); ins5(v1,t0,t1,t2,t3,t4);
    ins5(v2,t0,t1,t2,t3,t4); ins5(v3,t0,t1,t2,t3,t4);
  }
#pragma unroll
  for (int m = 1; m < 64; m <<= 1){
    float b0=__shfl_xor(t0,m,64), b1=__shfl_xor(t1,m,64), b2=__shfl_xor(t2,m,64),
          b3=__shfl_xor(t3,m,64), b4=__shfl_xor(t4,m,64);
    merge5(t0,t1,t2,t3,t4,b0,b1,b2,b3,b4);
    vmx = fmaxf(vmx, __shfl_xor(vmx,m,64));
  }
  __shared__ float w5[4][5];
  __shared__ float wm[4];
  int lane = tid & 63, wid = tid >> 6;
  if (lane == 0){ w5[wid][0]=t0; w5[wid][1]=t1; w5[wid][2]=t2; w5[wid][3]=t3; w5[wid][4]=t4; wm[wid]=vmx; }
  __syncthreads();
  if (tid == 0){
    float a0=w5[0][0],a1=w5[0][1],a2=w5[0][2],a3=w5[0][3],a4=w5[0][4];
    for (int w = 1; w < 4; ++w) merge5(a0,a1,a2,a3,a4, w5[w][0],w5[w][1],w5[w][2],w5[w][3],w5[w][4]);
    float d0=sqrtf(a0)*0.0625f, d1=sqrtf(a1)*0.0625f, d2=sqrtf(a2)*0.0625f,
          d3=sqrtf(a3)*0.0625f, d4=sqrtf(a4)*0.0625f;
    float s = d0*d0; s += d1*d1; s += d2*d2; s += d3*d3; s += d4*d4;
    density[b*NT + i] = expf(-(s / 5.0f));
    float vm = fmaxf(fmaxf(wm[0],wm[1]), fmaxf(wm[2],wm[3]));
    atomicMax(vmax + b, __float_as_int(vm));
  }
}

__global__ __launch_bounds__(256) void parent_all(const float* __restrict__ G, size_t gstride,
                                                  const float* __restrict__ sq,
                                                  const float* __restrict__ density, const int* __restrict__ vmax,
                                                  float* __restrict__ score, int b_base){
  int b = b_base + blockIdx.y;
  const float* Gb = G + (size_t)blockIdx.y*gstride;
  int i = blockIdx.x;
  int tid = threadIdx.x;
  const float* sqb = sq + b*NT;
  const float* den = density + b*NT;
  float sqi = sqb[i];
  float di = den[i];
  const float* row = Gb + (size_t)i*NT;
  float minv = INFINITY;
  for (int j = tid*4; j < NT; j += 1024){
    float4 g4 = *(const float4*)(row + j);
    float4 s4 = *(const float4*)(sqb + j);
    float4 d4 = *(const float4*)(den + j);
    float v0 = fmaxf(sqi + s4.x - 2.0f*g4.x, 0.0f);
    float v1 = fmaxf(sqi + s4.y - 2.0f*g4.y, 0.0f);
    float v2 = fmaxf(sqi + s4.z - 2.0f*g4.z, 0.0f);
    float v3 = fmaxf(sqi + s4.w - 2.0f*g4.w, 0.0f);
    minv = fminf(minv, (d4.x > di) ? v0 : INFINITY);
    minv = fminf(minv, (d4.y > di) ? v1 : INFINITY);
    minv = fminf(minv, (d4.z > di) ? v2 : INFINITY);
    minv = fminf(minv, (d4.w > di) ? v3 : INFINITY);
  }
#pragma unroll
  for (int m = 1; m < 64; m <<= 1) minv = fminf(minv, __shfl_xor(minv,m,64));
  __shared__ float wmn[4];
  int lane = tid & 63, wid = tid >> 6;
  if (lane == 0) wmn[wid] = minv;
  __syncthreads();
  if (tid == 0){
    float mv = fminf(fminf(wmn[0],wmn[1]), fminf(wmn[2],wmn[3]));
    float dmax = sqrtf(__int_as_float(vmax[b])) * 0.0625f;
    float dp = isinf(mv) ? dmax : sqrtf(mv) * 0.0625f;
    score[b*NT + i] = dp * di;
  }
}

// bitonic sort 4096 (score desc, idx asc); 2 pairs/thread/step; builds inverse map.
__global__ __launch_bounds__(1024) void topk_all(const float* __restrict__ score, int* __restrict__ idx_down,
                                                 int* __restrict__ inv, int b_base){
  __shared__ float ss[4096];
  __shared__ int ii[4096];
  int b = b_base + blockIdx.x;
  int tid = threadIdx.x;
  for (int t = tid; t < 4096; t += 1024){ ss[t] = score[b*NT + t]; ii[t] = t; inv[b*NT + t] = -1; }
  for (int k = 2; k <= 4096; k <<= 1){
    for (int j = k >> 1; j > 0; j >>= 1){
      __syncthreads();
#pragma unroll
      for (int vv = 0; vv < 2; ++vv){
        int v = tid + vv*1024;
        int i1 = 2*v - (v & (j-1));
        int i2 = i1 + j;
        float s1 = ss[i1], s2 = ss[i2];
        int a1 = ii[i1], a2 = ii[i2];
        bool lt = (s1 > s2) || (s1 == s2 && a1 < a2);
        bool up = ((i1 & k) == 0);
        if (up ? !lt : lt){ ss[i1]=s2; ss[i2]=s1; ii[i1]=a2; ii[i2]=a1; }
      }
    }
  }
  __syncthreads();
  if (tid < MC){
    int tok = ii[tid];
    idx_down[b*MC + tid] = tok;
    inv[b*NT + tok] = tid;
  }
}

// assign: block = 16 j x 16 m-chunks (64 m each, ascending); grid 256 x gy.
__global__ __launch_bounds__(256) void assign_all(const float* __restrict__ G, size_t gstride,
                                                  const float* __restrict__ sq,
                                                  const int* __restrict__ idx_down, const int* __restrict__ inv,
                                                  const float* __restrict__ wt,
                                                  int* __restrict__ idx_cluster, float* __restrict__ allw,
                                                  int b_base){
  int b = b_base + blockIdx.y;
  const float* Gb = G + (size_t)blockIdx.y*gstride;
  int jl = threadIdx.x & 15, mq = threadIdx.x >> 4;
  int j = blockIdx.x * 16 + jl;
  const float* sqb = sq + b*NT;
  float sqj = sqb[j];
  const int* idb = idx_down + b*MC;
  float bestd = INFINITY; int bestm = 0x7fffffff;
  for (int m = mq*64; m < mq*64 + 64; ++m){
    int im = idb[m];
    float g = Gb[(size_t)im*NT + j];
    float v = fmaxf(sqb[im] + sqj - 2.0f*g, 0.0f);
    float d = sqrtf(v) * 0.0625f;
    if (d < bestd){ bestd = d; bestm = m; }
  }
  __shared__ float ld[16][17];
  __shared__ int lm[16][17];
  ld[mq][jl] = bestd; lm[mq][jl] = bestm;
  __syncthreads();
  if (mq == 0){
    for (int q = 1; q < 16; ++q){
      float d2 = ld[q][jl]; int m2 = lm[q][jl];
      if (d2 < bestd || (d2 == bestd && m2 < bestm)){ bestd = d2; bestm = m2; }
    }
    int iv = inv[b*NT + j];
    int final_m = (iv >= 0) ? iv : bestm;
    idx_cluster[b*NT + j] = final_m;
    atomicAdd(&allw[b*MC + final_m], wt[b*NT + j]);
  }
}

// ---------------- merge + outputs ----------------
__global__ __launch_bounds__(256) void xdown_kernel(const int* __restrict__ idx_cluster,
                                                    const float* __restrict__ wt, const float* __restrict__ allw,
                                                    const float* __restrict__ xt, float* __restrict__ out0){
  int bn = blockIdx.x;
  int d = threadIdx.x;
  int b = bn >> 12;
  int ic = idx_cluster[bn];
  float nw = wt[bn] / (allw[b*MC + ic] + EPS_F);
  float v = xt[(size_t)bn*DOUT + d] * nw;
  atomicAdd(&out0[((size_t)(b*MC + ic))*DOUT + d], v);
}
__global__ __launch_bounds__(256) void out12a_kernel(const int* __restrict__ idx_agg, const int* __restrict__ idx_cluster,
                                                     const float* __restrict__ aggw,
                                                     const float* __restrict__ wt, const float* __restrict__ allw,
                                                     float* __restrict__ awd, int* __restrict__ awdmax,
                                                     float* __restrict__ out1){
  __shared__ float red[4];
  int lin = blockIdx.x * 256 + threadIdx.x;
  int b = lin >> 12;
  int ia = idx_agg[lin];
  int ic = idx_cluster[b*NT + ia];
  out1[lin] = (float)ic;
  float nw = wt[b*NT + ia] / (allw[b*MC + ic] + EPS_F);
  float v = aggw[lin] * nw;
  awd[lin] = v;
  float wv = v;
#pragma unroll
  for (int m = 1; m < 64; m <<= 1) wv = fmaxf(wv, __shfl_xor(wv, m, 64));
  int lane = threadIdx.x & 63, wid = threadIdx.x >> 6;
  if (lane == 0) red[wid] = wv;
  __syncthreads();
  if (threadIdx.x == 0){
    float bm = fmaxf(fmaxf(red[0], red[1]), fmaxf(red[2], red[3]));
    atomicMax(&awdmax[b], __float_as_int(bm));
  }
}
__global__ __launch_bounds__(256) void out2_kernel(const float* __restrict__ awd, const int* __restrict__ awdmax,
                                                   float* __restrict__ out2){
  int lin = blockIdx.x * 256 + threadIdx.x;
  int b = lin >> 12;
  out2[lin] = awd[lin] / __int_as_float(awdmax[b]);
}

extern "C" void kernel_launch(void* const* d_in, const int* in_sizes, int n_in,
                              void* d_out, int out_size, void* d_ws, size_t ws_size,
                              hipStream_t stream) {
  const float* x      = (const float*)d_in[0];
  const float* loc    = (const float*)d_in[1];
  const int*   idxagg = (const int*)d_in[2];
  const float* aggw   = (const float*)d_in[3];
  const float* convw  = (const float*)d_in[7];
  const float* convb  = (const float*)d_in[8];
  const float* skipw  = (const float*)d_in[9];
  const float* lng    = (const float*)d_in[10];
  const float* lnb    = (const float*)d_in[11];
  const float* confw  = (const float*)d_in[12];
  const float* confb  = (const float*)d_in[13];

  char* ws = (char*)d_ws;
  float* w_xmap  = (float*)(ws + OFF_XMAP);
  float* w_cnt   = (float*)(ws + OFF_CNT);
  float* w_tot   = (float*)(ws + OFF_TOT);
  float* w_allw  = (float*)(ws + OFF_ALLW);
  int*   w_vmax  = (int*)  (ws + OFF_VMAX);
  int*   w_awdm  = (int*)  (ws + OFF_AWDM);
  float* w_ymap  = (float*)(ws + OFF_YMAP);
  float* w_xt    = (float*)(ws + OFF_XT);
  float* w_sq    = (float*)(ws + OFF_SQ);
  float* w_den   = (float*)(ws + OFF_DEN);
  float* w_score = (float*)(ws + OFF_SCORE);
  float* w_wt    = (float*)(ws + OFF_WT);
  float* w_awd   = (float*)(ws + OFF_AWD);
  int*   w_idxd  = (int*)  (ws + OFF_IDXD);
  int*   w_idxc  = (int*)  (ws + OFF_IDXC);
  int*   w_inv   = (int*)  (ws + OFF_INV);
  float* w_wtr   = (float*)(ws + OFF_WTR);
  float* w_swt   = (float*)(ws + OFF_SWT);
  float* w_p     = (float*)(ws + OFF_P);
  float* w_g     = (float*)(ws + OFF_G);

  int gcount = 1;
  for (int k = 4; k >= 1; --k){
    if (OFF_G + (size_t)k*GSZB <= ws_size){ gcount = k; break; }
  }

  float* out0 = (float*)d_out;
  float* out1 = out0 + NB*MC*DOUT;
  float* out2 = out1 + NB*NT;

  hipMemsetAsync(ws, 0, ZERO_BYTES, stream);
  hipMemsetAsync(out0, 0, (size_t)NB*MC*DOUT*sizeof(float), stream);

  t2m_scatter<<<NB*NT*CI/256, 256, 0, stream>>>(x, loc, idxagg, aggw, w_xmap, w_cnt, w_tot);
  wprep_kernel<<<1280, 256, 0, stream>>>(convw, skipw, w_wtr, w_swt);
  im2col_kernel<<<2048, 256, 0, stream>>>(w_xmap, w_cnt, w_p);
  conv_gemm<<<dim3(8, 64), 256, 0, stream>>>(w_p, w_wtr, convb, w_ymap);
  skip_kernel<<<NB*NT/8, 256, 0, stream>>>(x, w_swt, w_xt);
  m2t_scatter<<<NB*NT, 256, 0, stream>>>(w_ymap, loc, idxagg, aggw, w_tot, w_xt);
  ln_kernel<<<NB*NT, 256, 0, stream>>>(w_xt, lng, lnb, confw, confb, w_sq, w_wt);

  for (int g0 = 0; g0 < NB; g0 += gcount){
    int gy = (NB - g0 < gcount) ? (NB - g0) : gcount;
    gram64     <<<dim3(2080, gy), 256, 0, stream>>>(w_xt, w_g, g0, GSZ);
    density_all<<<dim3(NT, gy), 256, 0, stream>>>(w_g, GSZ, w_sq, w_den, w_vmax, g0);
    parent_all <<<dim3(NT, gy), 256, 0, stream>>>(w_g, GSZ, w_sq, w_den, w_vmax, w_score, g0);
    topk_all   <<<gy, 1024, 0, stream>>>(w_score, w_idxd, w_inv, g0);
    assign_all <<<dim3(256, gy), 256, 0, stream>>>(w_g, GSZ, w_sq, w_idxd, w_inv, w_wt, w_idxc, w_allw, g0);
  }

  xdown_kernel<<<NB*NT, 256, 0, stream>>>(w_idxc, w_wt, w_allw, w_xt, out0);
  out12a_kernel<<<NB*NT/256, 256, 0, stream>>>(idxagg, w_idxc, aggw, w_wt, w_allw, w_awd, w_awdm, out1);
  out2_kernel<<<NB*NT/256, 256, 0, stream>>>(w_awd, w_awdm, out2);

  (void)in_sizes; (void)n_in; (void)out_size;
}